// Round 12
// baseline (160.958 us; speedup 1.0000x reference)
//
#include <hip/hip_runtime.h>
#include <math.h>

// TokenChoiceTopKRouter, round 12: 3 blocks/CU for latency overlap.
//
// R11 (161 us fused): VGPR 52, no spill, conflicts small -- but occupancy 20%,
// both pipes idle: ONE 8-wave barrier convoy per CU; every vmcnt stall idles
// the CU. R12: block = 32 tok x 64 exp, 256 thr (4 waves), grid 512, chunk
// 32k, 4 x 12 KB LDS bufs = 48 KB -> 3 blocks/CU = 3 independent convoys
// whose stalls overlap. Staging uniform: 3 GLD16/thread/stage -> counted
// vmcnt 6/3/0 (never 0 in steady loop, T4). Same proven numerics (bf16 hi/lo
// 3-pass MFMA, absmax 50), proven epilogue + wsH/k5 histogram.

constexpr int DIM = 4096;
constexpr int NE  = 64;
constexpr int NCH = 128;                         // 32k chunks
constexpr size_t WSB_BYTES = 1048576;            // packed B stream (1 MB)

typedef __attribute__((ext_vector_type(8))) short bf16x8;
typedef __attribute__((ext_vector_type(4))) float f32x4;

#define GLD16(gp, lp)                                                        \
  __builtin_amdgcn_global_load_lds(                                          \
      (const __attribute__((address_space(1))) unsigned int*)(gp),           \
      (__attribute__((address_space(3))) unsigned int*)(lp), 16, 0, 0)

// ---------- k1: pack w into hi/lo B-fragment stream (R6/R10-proven) ---------
// 16B-unit u = sl*512 + f*64 + lane (sl = 32k step 0..127, f = et*2 + hl).
// Content: e = et*16 + (lane&15), k = sl*32 + 8*(lane>>4) (+j), hi/lo bf16.
__global__ void pack_w(const float* __restrict__ w, ushort* __restrict__ wsB) {
  const int u  = blockIdx.x * 256 + threadIdx.x;   // 65536 units
  const int l  = u & 63;
  const int f  = (u >> 6) & 7;
  const int sl = u >> 9;                           // 0..127
  const int et = f >> 1, hl = f & 1;
  const int e  = et * 16 + (l & 15);
  const int k  = sl * 32 + 8 * (l >> 4);
  const float* src = w + (size_t)e * DIM + k;
  ushort v[8];
#pragma unroll
  for (int j = 0; j < 8; ++j) {
    float xv = src[j];
    unsigned xb = __float_as_uint(xv);
    unsigned hb = xb & 0xffff0000u;                // exact hi (truncation)
    if (hl == 0) {
      v[j] = (ushort)(hb >> 16);
    } else {
      float lf = xv - __uint_as_float(hb);
      unsigned lb = __float_as_uint(lf);
      lb = lb + 0x7fffu + ((lb >> 16) & 1u);       // RNE to bf16
      v[j] = (ushort)(lb >> 16);
    }
  }
  ushort* d = wsB + (size_t)u * 8;
#pragma unroll
  for (int j = 0; j < 8; ++j) d[j] = v[j];
}

// ---------- shared helper: f32x8 -> hi/lo bf16x8 ----------
__device__ __forceinline__ void split8(const float4& a0, const float4& a1,
                                       bf16x8& ahi, bf16x8& alo) {
  float av[8] = {a0.x, a0.y, a0.z, a0.w, a1.x, a1.y, a1.z, a1.w};
#pragma unroll
  for (int j = 0; j < 8; ++j) {
    unsigned xb = __float_as_uint(av[j]);
    unsigned hb = xb & 0xffff0000u;
    float lf = av[j] - __uint_as_float(hb);
    unsigned lb = __float_as_uint(lf);
    lb = lb + 0x7fffu + ((lb >> 16) & 1u);
    ahi[j] = (short)(hb >> 16);
    alo[j] = (short)(lb >> 16);
  }
}

// ---------- fused main kernel: 32 tok x 64 exp, 4 waves, 3 blocks/CU --------
// LDS buf q = c&3 at q*12288: x 4 KB (32 rows x 128 B, k-units src-swizzled
// by ks^(r&7)), B 8 KB at +4096 ([f][lane] 16B units). Epilogue reuse:
// logits f32[32][64] at 0, hist f32[64] at 8192.
__global__ __launch_bounds__(256, 3)
void router_fused(const float* __restrict__ x, const char* __restrict__ wsB,
                  const float* __restrict__ bias,
                  float* __restrict__ out_scores, float* __restrict__ out_idx,
                  float* __restrict__ wsH) {
  __shared__ char lds[49152];
  const int tid  = threadIdx.x;
  const int wv   = tid >> 6;
  const int lane = tid & 63;
  const int tt   = wv & 1;            // token tile 0..1
  const int eh   = wv >> 1;           // expert half 0..1
  const int col  = lane & 15;
  const int kq   = lane >> 4;
  const int tok0 = blockIdx.x * 32;

  // x staging: unit (r = tid>>3, ks = tid&7); source k-unit pre-swizzled.
  const int r  = tid >> 3;            // 0..31
  const int ks = tid & 7;
  const int su = ks ^ (r & 7);
  const float* gxrow = x + (size_t)(tok0 + r) * DIM + su * 4;   // + c*32
  const char*  gb    = wsB;                                     // + c*8192

  f32x4 acc[2];
  acc[0] = (f32x4){0.f, 0.f, 0.f, 0.f};
  acc[1] = (f32x4){0.f, 0.f, 0.f, 0.f};

#define STAGE(cc)                                                            \
  do {                                                                       \
    char* lq = lds + ((cc) & 3) * 12288;                                     \
    GLD16(gxrow + (cc) * 32, lq + tid * 16);                                 \
    GLD16(gb + (size_t)(cc) * 8192 + tid * 16, lq + 4096 + tid * 16);        \
    GLD16(gb + (size_t)(cc) * 8192 + 4096 + tid * 16,                        \
          lq + 8192 + tid * 16);                                             \
  } while (0)

  STAGE(0);
  STAGE(1);

  // A-read constants: row arow (stride 128 B), k-units (kq*2+i)^(arow&7)
  const int arow = tt * 16 + col;
  const int u0   = (kq * 2 + 0) ^ (arow & 7);
  const int u1   = (kq * 2 + 1) ^ (arow & 7);

#pragma unroll 1
  for (int c = 0; c < NCH; ++c) {
    if (c + 2 < NCH) {
      STAGE(c + 2);
      asm volatile("s_waitcnt vmcnt(6)" ::: "memory");  // c done; c+1,c+2 fly
    } else if (c + 2 == NCH) {
      asm volatile("s_waitcnt vmcnt(3)" ::: "memory");
    } else {
      asm volatile("s_waitcnt vmcnt(0)" ::: "memory");
    }
    __builtin_amdgcn_s_barrier();       // raw: no compiler vmcnt(0) drain
    __builtin_amdgcn_sched_barrier(0);  // keep ds_reads below the barrier

    const char* lq = lds + (c & 3) * 12288;
    float4 q0 = *(const float4*)(lq + arow * 128 + u0 * 16);
    float4 q1 = *(const float4*)(lq + arow * 128 + u1 * 16);
    bf16x8 ahi, alo;
    split8(q0, q1, ahi, alo);
    const char* lb = lq + 4096;
#pragma unroll
    for (int et2 = 0; et2 < 2; ++et2) {
      const int f = (eh * 2 + et2) * 2;
      bf16x8 bh = *(const bf16x8*)(lb + (f + 0) * 1024 + lane * 16);
      bf16x8 bl = *(const bf16x8*)(lb + (f + 1) * 1024 + lane * 16);
      acc[et2] = __builtin_amdgcn_mfma_f32_16x16x32_bf16(ahi, bh, acc[et2], 0, 0, 0);
      acc[et2] = __builtin_amdgcn_mfma_f32_16x16x32_bf16(alo, bh, acc[et2], 0, 0, 0);
      acc[et2] = __builtin_amdgcn_mfma_f32_16x16x32_bf16(ahi, bl, acc[et2], 0, 0, 0);
    }
  }
#undef STAGE

  // ---- epilogue: full-K logits, 16 tok x 32 exp per wave ----
  __syncthreads();                         // full drain; LDS reusable
  float* logits = (float*)lds;             // 8 KB (32 x 64)
  float* hist   = (float*)(lds + 8192);    // 256 B
  if (tid < 64) hist[tid] = 0.f;
  // D layout (m89/R6-verified): e-col = et*16+col, token-row = 4*kq+r
#pragma unroll
  for (int et2 = 0; et2 < 2; ++et2)
#pragma unroll
    for (int rr = 0; rr < 4; ++rr) {
      int t = tt * 16 + 4 * kq + rr;
      int e = eh * 32 + et2 * 16 + col;
      logits[t * 64 + ((e + t) & 63)] = acc[et2][rr];
    }
  __syncthreads();

  // ---- sigmoid + biased top-8 + normalize + LDS hist (proven tail) ----
  if (tid < 32) {
    const int t = tid, gt = tok0 + t;
    float key[8], sv[8];
    int   idx[8];
#pragma unroll
    for (int j = 0; j < 8; ++j) { key[j] = -1e30f; sv[j] = 0.f; idx[j] = 0; }

    for (int e = 0; e < NE; ++e) {
      float l = logits[t * 64 + ((e + t) & 63)];
      float s = 1.0f / (1.0f + expf(-l));
      float k = s + bias[e];
      // bubble-insert; strict > keeps lower index on ties (lax.top_k order)
      float ck = k, cv = s; int ci = e;
#pragma unroll
      for (int j = 0; j < 8; ++j) {
        bool g = ck > key[j];
        float tk = key[j], tv = sv[j]; int ti = idx[j];
        key[j] = g ? ck : tk; sv[j] = g ? cv : tv; idx[j] = g ? ci : ti;
        ck = g ? tk : ck;     cv = g ? tv : cv;    ci = g ? ti : ci;
      }
    }

    float sum = 1e-20f;
#pragma unroll
    for (int j = 0; j < 8; ++j) sum += sv[j];
    float inv = 1.0f / sum;
#pragma unroll
    for (int j = 0; j < 8; ++j) {
      out_scores[gt * 8 + j] = sv[j] * inv;
      out_idx[gt * 8 + j]    = (float)idx[j];
      atomicAdd(&hist[idx[j]], 1.0f);      // LDS atomic
    }
  }
  __syncthreads();
  if (tid < 64) wsH[(size_t)blockIdx.x * NE + tid] = hist[tid];
}

// ---------- k5: reduce per-block histograms -> counts (no atomics) ----------
__global__ __launch_bounds__(256)
void router_k5(const float* __restrict__ wsH, float* __restrict__ counts,
               int nblk) {
  __shared__ float part[256];
  const int e = threadIdx.x & 63, p = threadIdx.x >> 6;
  float s = 0.f;
  for (int b = p; b < nblk; b += 4) s += wsH[(size_t)b * NE + e];
  part[p * 64 + e] = s;
  __syncthreads();
  if (threadIdx.x < 64)
    counts[e] = part[e] + part[64 + e] + part[128 + e] + part[192 + e];
}

// ---------- R6 proven mid-fallback (ws >= 1 MB): direct B-stream MFMA ------
__global__ __launch_bounds__(512, 2)
void router_mfma(const float* __restrict__ x, const ushort* __restrict__ ws,
                 const float* __restrict__ bias,
                 float* __restrict__ out_scores, float* __restrict__ out_idx,
                 float* __restrict__ counts) {
  __shared__ float logits[64 * 64];
  const int tid  = threadIdx.x;
  const int lane = tid & 63;
  const int wv   = tid >> 6;
  const int wt   = wv & 3;
  const int wk   = wv >> 2;
  const int tok0 = blockIdx.x * 64;
  const int col  = lane & 15;
  const int kq   = lane >> 4;
  const float* xrow = x + (size_t)(tok0 + wt * 16 + col) * DIM + wk * 2048 + 8 * kq;
  const ushort* wsl = ws + (size_t)lane * 8;
  f32x4 acc[4];
#pragma unroll
  for (int et = 0; et < 4; ++et) acc[et] = (f32x4){0.f, 0.f, 0.f, 0.f};
  const int s0 = wk * 64;
  float4 a0c = *(const float4*)(xrow + 0);
  float4 a1c = *(const float4*)(xrow + 4);
  bf16x8 bc[8];
#pragma unroll
  for (int f = 0; f < 8; ++f)
    bc[f] = *(const bf16x8*)(wsl + (size_t)(s0 * 8 + f) * 64 * 8);
#pragma unroll 1
  for (int ls = 0; ls < 64; ls += 2) {
    const int so = s0 + ls + 1;
    float4 a0o = *(const float4*)(xrow + (ls + 1) * 32);
    float4 a1o = *(const float4*)(xrow + (ls + 1) * 32 + 4);
    bf16x8 bo[8];
#pragma unroll
    for (int f = 0; f < 8; ++f)
      bo[f] = *(const bf16x8*)(wsl + (size_t)(so * 8 + f) * 64 * 8);
    {
      bf16x8 ahi, alo;
      split8(a0c, a1c, ahi, alo);
#pragma unroll
      for (int et = 0; et < 4; ++et) {
        acc[et] = __builtin_amdgcn_mfma_f32_16x16x32_bf16(ahi, bc[et * 2 + 0], acc[et], 0, 0, 0);
        acc[et] = __builtin_amdgcn_mfma_f32_16x16x32_bf16(alo, bc[et * 2 + 0], acc[et], 0, 0, 0);
        acc[et] = __builtin_amdgcn_mfma_f32_16x16x32_bf16(ahi, bc[et * 2 + 1], acc[et], 0, 0, 0);
      }
    }
    if (ls + 2 < 64) {
      const int se = s0 + ls + 2;
      a0c = *(const float4*)(xrow + (ls + 2) * 32);
      a1c = *(const float4*)(xrow + (ls + 2) * 32 + 4);
#pragma unroll
      for (int f = 0; f < 8; ++f)
        bc[f] = *(const bf16x8*)(wsl + (size_t)(se * 8 + f) * 64 * 8);
    }
    {
      bf16x8 ahi, alo;
      split8(a0o, a1o, ahi, alo);
#pragma unroll
      for (int et = 0; et < 4; ++et) {
        acc[et] = __builtin_amdgcn_mfma_f32_16x16x32_bf16(ahi, bo[et * 2 + 0], acc[et], 0, 0, 0);
        acc[et] = __builtin_amdgcn_mfma_f32_16x16x32_bf16(alo, bo[et * 2 + 0], acc[et], 0, 0, 0);
        acc[et] = __builtin_amdgcn_mfma_f32_16x16x32_bf16(ahi, bo[et * 2 + 1], acc[et], 0, 0, 0);
      }
    }
  }
  if (wk == 0) {
#pragma unroll
    for (int et = 0; et < 4; ++et)
#pragma unroll
      for (int r = 0; r < 4; ++r) {
        int t = wt * 16 + 4 * kq + r;
        int e = et * 16 + col;
        logits[t * 64 + ((e + t) & 63)] = acc[et][r];
      }
  }
  __syncthreads();
  if (wk == 1) {
#pragma unroll
    for (int et = 0; et < 4; ++et)
#pragma unroll
      for (int r = 0; r < 4; ++r) {
        int t = wt * 16 + 4 * kq + r;
        int e = et * 16 + col;
        logits[t * 64 + ((e + t) & 63)] += acc[et][r];
      }
  }
  __syncthreads();
  if (tid < 64) {
    const int t = tid, gt = tok0 + t;
    float key[8], sv[8]; int idx[8];
#pragma unroll
    for (int j = 0; j < 8; ++j) { key[j] = -1e30f; sv[j] = 0.f; idx[j] = 0; }
    for (int e = 0; e < NE; ++e) {
      float l = logits[t * 64 + ((e + t) & 63)];
      float s = 1.0f / (1.0f + expf(-l));
      float k = s + bias[e];
      float ck = k, cv = s; int ci = e;
#pragma unroll
      for (int j = 0; j < 8; ++j) {
        bool g = ck > key[j];
        float tk = key[j], tv = sv[j]; int ti = idx[j];
        key[j] = g ? ck : tk; sv[j] = g ? cv : tv; idx[j] = g ? ci : ti;
        ck = g ? tk : ck;     cv = g ? tv : cv;    ci = g ? ti : ci;
      }
    }
    float sum = 1e-20f;
#pragma unroll
    for (int j = 0; j < 8; ++j) sum += sv[j];
    float inv = 1.0f / sum;
#pragma unroll
    for (int j = 0; j < 8; ++j) {
      out_scores[gt * 8 + j] = sv[j] * inv;
      out_idx[gt * 8 + j]    = (float)idx[j];
      atomicAdd(&counts[idx[j]], 1.0f);
    }
  }
}

// ---------- R5 proven last-resort fallback (fp32 scalar-w) ----------
constexpr int KSTEP = 32;
constexpr int FNSTEP = DIM / KSTEP;
constexpr int ROWF4 = 9;
constexpr int BUF4  = 64 * ROWF4;

__global__ __launch_bounds__(512, 2)
void router_fallback(const float* __restrict__ x, const float* __restrict__ w,
                     const float* __restrict__ bias,
                     float* __restrict__ out_scores, float* __restrict__ out_idx,
                     float* __restrict__ counts) {
  __shared__ float4 lds4[2 * BUF4];
  float* ldsf = (float*)lds4;
  const int tid  = threadIdx.x;
  const int lane = tid & 63;
  const int eg   = __builtin_amdgcn_readfirstlane(tid >> 6);
  const int tok0 = blockIdx.x * 64;
  const int r0 = tid >> 3, j0 = tid & 7;
  const float* gp = &x[(size_t)(tok0 + r0) * DIM + j0 * 4];
  const int l0 = r0 * ROWF4 + j0;
  float acc[8];
#pragma unroll
  for (int e = 0; e < 8; ++e) acc[e] = 0.f;
  lds4[l0] = *(const float4*)gp;
  __syncthreads();
  const float* wbase = w + (size_t)eg * 8 * DIM;
#pragma unroll 1
  for (int c = 0; c < FNSTEP; ++c) {
    float4 pf;
    if (c + 1 < FNSTEP) pf = *(const float4*)(gp + (c + 1) * KSTEP);
    float xr[KSTEP];
    {
      const float4* xrow = lds4 + (c & 1) * BUF4 + lane * ROWF4;
#pragma unroll
      for (int i = 0; i < 8; ++i) {
        float4 q = xrow[i];
        xr[4 * i + 0] = q.x; xr[4 * i + 1] = q.y;
        xr[4 * i + 2] = q.z; xr[4 * i + 3] = q.w;
      }
    }
#pragma unroll
    for (int e = 0; e < 8; ++e) {
      const float* wr = wbase + e * DIM + c * KSTEP;
#pragma unroll
      for (int k = 0; k < KSTEP; ++k) acc[e] = fmaf(xr[k], wr[k], acc[e]);
    }
    if (c + 1 < FNSTEP) lds4[((c + 1) & 1) * BUF4 + l0] = pf;
    __syncthreads();
  }
#pragma unroll
  for (int j = 0; j < 8; ++j) {
    int e = eg * 8 + j;
    ldsf[lane * 64 + ((e + lane) & 63)] = acc[j];
  }
  __syncthreads();
  if (tid < 64) {
    const int t = tid, gt = tok0 + t;
    float key[8], sv[8]; int idx[8];
#pragma unroll
    for (int j = 0; j < 8; ++j) { key[j] = -1e30f; sv[j] = 0.f; idx[j] = 0; }
    for (int e = 0; e < NE; ++e) {
      float l = ldsf[t * 64 + ((e + t) & 63)];
      float s = 1.0f / (1.0f + expf(-l));
      float k = s + bias[e];
      float ck = k, cv = s; int ci = e;
#pragma unroll
      for (int j = 0; j < 8; ++j) {
        bool g = ck > key[j];
        float tk = key[j], tv = sv[j]; int ti = idx[j];
        key[j] = g ? ck : tk; sv[j] = g ? cv : tv; idx[j] = g ? ci : ti;
        ck = g ? tk : ck;     cv = g ? tv : cv;    ci = g ? ti : ci;
      }
    }
    float sum = 1e-20f;
#pragma unroll
    for (int j = 0; j < 8; ++j) sum += sv[j];
    float inv = 1.0f / sum;
#pragma unroll
    for (int j = 0; j < 8; ++j) {
      out_scores[gt * 8 + j] = sv[j] * inv;
      out_idx[gt * 8 + j]    = (float)idx[j];
      atomicAdd(&counts[idx[j]], 1.0f);
    }
  }
}

extern "C" void kernel_launch(void* const* d_in, const int* in_sizes, int n_in,
                              void* d_out, int out_size, void* d_ws, size_t ws_size,
                              hipStream_t stream) {
  const float* x    = (const float*)d_in[0];
  const float* w    = (const float*)d_in[1];
  const float* bias = (const float*)d_in[2];

  const int ntok = in_sizes[0] / DIM;              // 16384
  float* out        = (float*)d_out;
  float* out_scores = out;
  float* out_idx    = out + ntok * 8;
  float* counts     = out + 2 * ntok * 8;

  hipMemsetAsync(counts, 0, NE * sizeof(float), stream);

  const int    nblk      = ntok / 32;              // 512
  const size_t wsh_bytes = (size_t)nblk * NE * sizeof(float);  // 128 KB
  const size_t need = WSB_BYTES + wsh_bytes;

  if (ws_size >= need && (ntok % 32) == 0) {
    ushort* wsB = (ushort*)d_ws;
    float*  wsH = (float*)((char*)d_ws + WSB_BYTES);
    hipLaunchKernelGGL(pack_w, dim3(256), dim3(256), 0, stream, w, wsB);
    hipLaunchKernelGGL(router_fused, dim3(nblk), dim3(256), 0, stream,
                       x, (const char*)wsB, bias, out_scores, out_idx, wsH);
    hipLaunchKernelGGL(router_k5, dim3(1), dim3(256), 0, stream,
                       wsH, counts, nblk);
  } else if (ws_size >= WSB_BYTES) {
    ushort* wsB = (ushort*)d_ws;
    hipLaunchKernelGGL(pack_w, dim3(256), dim3(256), 0, stream, w, wsB);
    hipLaunchKernelGGL(router_mfma, dim3(ntok / 64), dim3(512), 0, stream,
                       x, wsB, bias, out_scores, out_idx, counts);
  } else {
    hipLaunchKernelGGL(router_fallback, dim3(ntok / 64), dim3(512), 0, stream,
                       x, w, bias, out_scores, out_idx, counts);
  }
}

// Round 13
// 127.856 us; speedup vs baseline: 1.2589x; 1.2589x over previous
//
#include <hip/hip_runtime.h>
#include <math.h>

// TokenChoiceTopKRouter, round 13: compiler-invisible ds_reads -> real
// counted-vmcnt pipeline.
//
// R11/R12 evidence: period ~1.3 us/chunk regardless of chunk size, TLP,
// swizzle -> the compiler inserts vmcnt(0) before the HIP-level ds_reads
// (cannot prove global_load_lds writes don't alias) so every iteration waits
// on the JUST-issued stage. Fix: fragment reads via inline-asm ds_read_b128
// (AS3), one lgkmcnt(0)+sched_barrier(0) (rule #18). 3 bufs x 64k chunks
// (64 iters), stage-after-barrier, vmcnt(6) steady (T4), 72 KB LDS ->
// 2 blocks/CU (grid 512). Proven numerics (bf16 hi/lo 3-pass, absmax 50),
// proven epilogue + wsH/k5 histogram (no global atomics).

constexpr int DIM = 4096;
constexpr int NE  = 64;
constexpr int NCH = 64;                          // 64k chunks
constexpr size_t WSB_BYTES = 1048576;            // packed B stream (1 MB)

typedef __attribute__((ext_vector_type(8))) short bf16x8;
typedef __attribute__((ext_vector_type(4))) float f32x4;

#define GLD16(gp, lp)                                                        \
  __builtin_amdgcn_global_load_lds(                                          \
      (const __attribute__((address_space(1))) unsigned int*)(gp),           \
      (__attribute__((address_space(3))) unsigned int*)(lp), 16, 0, 0)

__device__ __forceinline__ f32x4 dsr_f4(const char* p) {
  f32x4 r;
  asm volatile("ds_read_b128 %0, %1"
               : "=v"(r)
               : "v"((const __attribute__((address_space(3))) char*)p));
  return r;
}
__device__ __forceinline__ bf16x8 dsr_b8(const char* p) {
  bf16x8 r;
  asm volatile("ds_read_b128 %0, %1"
               : "=v"(r)
               : "v"((const __attribute__((address_space(3))) char*)p));
  return r;
}

// ---------- k1: pack w into hi/lo B-fragment stream (R6/R10-proven) ---------
// 16B-unit u = sl*512 + f*64 + lane (sl = 32k step 0..127, f = et*2 + hl).
// Content: e = et*16 + (lane&15), k = sl*32 + 8*(lane>>4) (+j), hi/lo bf16.
__global__ void pack_w(const float* __restrict__ w, ushort* __restrict__ wsB) {
  const int u  = blockIdx.x * 256 + threadIdx.x;   // 65536 units
  const int l  = u & 63;
  const int f  = (u >> 6) & 7;
  const int sl = u >> 9;                           // 0..127
  const int et = f >> 1, hl = f & 1;
  const int e  = et * 16 + (l & 15);
  const int k  = sl * 32 + 8 * (l >> 4);
  const float* src = w + (size_t)e * DIM + k;
  ushort v[8];
#pragma unroll
  for (int j = 0; j < 8; ++j) {
    float xv = src[j];
    unsigned xb = __float_as_uint(xv);
    unsigned hb = xb & 0xffff0000u;                // exact hi (truncation)
    if (hl == 0) {
      v[j] = (ushort)(hb >> 16);
    } else {
      float lf = xv - __uint_as_float(hb);
      unsigned lb = __float_as_uint(lf);
      lb = lb + 0x7fffu + ((lb >> 16) & 1u);       // RNE to bf16
      v[j] = (ushort)(lb >> 16);
    }
  }
  ushort* d = wsB + (size_t)u * 8;
#pragma unroll
  for (int j = 0; j < 8; ++j) d[j] = v[j];
}

// ---------- shared helper: two f32x4 -> hi/lo bf16x8 ----------
__device__ __forceinline__ void split8v(const f32x4& a0, const f32x4& a1,
                                        bf16x8& ahi, bf16x8& alo) {
#pragma unroll
  for (int j = 0; j < 8; ++j) {
    float av = (j < 4) ? a0[j] : a1[j - 4];
    unsigned xb = __float_as_uint(av);
    unsigned hb = xb & 0xffff0000u;
    float lf = av - __uint_as_float(hb);
    unsigned lb = __float_as_uint(lf);
    lb = lb + 0x7fffu + ((lb >> 16) & 1u);
    ahi[j] = (short)(hb >> 16);
    alo[j] = (short)(lb >> 16);
  }
}

// ---------- fused main kernel: 32 tok x 64 exp, 4 waves, 2 blocks/CU --------
// LDS buf q = c%3 at q*24576: x 8 KB (32 rows x 256 B, 16B-units src-swizzled
// by ks^(row&15)), B 16 KB at +8192 ([sl(2)][f(8)][lane] 16B units).
// Epilogue reuse: logits f32[32][64] at 0, hist f32[64] at 8192.
__global__ __launch_bounds__(256, 2)
void router_fused(const float* __restrict__ x, const char* __restrict__ wsB,
                  const float* __restrict__ bias,
                  float* __restrict__ out_scores, float* __restrict__ out_idx,
                  float* __restrict__ wsH) {
  __shared__ char lds[73728];
  const int tid  = threadIdx.x;
  const int wv   = tid >> 6;
  const int lane = tid & 63;
  const int tt   = wv & 1;            // token tile 0..1
  const int eh   = wv >> 1;           // expert half 0..1
  const int col  = lane & 15;
  const int kq   = lane >> 4;
  const int tok0 = blockIdx.x * 32;

  // x staging: unit q0=tid (rows 0..15), q1=tid+256 (rows 16..31).
  const int row0 = tid >> 4;
  const int ks0  = tid & 15;
  const int su0  = ks0 ^ (row0 & 15);           // row1&15 == row0&15
  const float* gx0 = x + (size_t)(tok0 + row0) * DIM + su0 * 4;       // +c*64
  const float* gx1 = gx0 + (size_t)16 * DIM;
  const int x_d0 = row0 * 256 + ks0 * 16;
  const int x_d1 = x_d0 + 4096;
  const char* gbs = wsB;                                              // +c*16384

  f32x4 acc[2];
  acc[0] = (f32x4){0.f, 0.f, 0.f, 0.f};
  acc[1] = (f32x4){0.f, 0.f, 0.f, 0.f};

#define STAGE(cc)                                                            \
  do {                                                                       \
    char* lq_ = lds + ((cc) % 3) * 24576;                                    \
    GLD16(gx0 + (cc) * 64, lq_ + x_d0);                                      \
    GLD16(gx1 + (cc) * 64, lq_ + x_d1);                                      \
    const char* gb_ = gbs + (size_t)(cc) * 16384 + tid * 16;                 \
    GLD16(gb_,          lq_ + 8192  + tid * 16);                             \
    GLD16(gb_ + 4096,   lq_ + 12288 + tid * 16);                             \
    GLD16(gb_ + 8192,   lq_ + 16384 + tid * 16);                             \
    GLD16(gb_ + 12288,  lq_ + 20480 + tid * 16);                             \
  } while (0)

  STAGE(0);
  STAGE(1);

  const int arow = tt * 16 + col;     // A row (256 B stride)
  const int am   = arow & 15;
  const int fb   = eh * 4;            // B frag base: f = eh*4 + et2*2 + hl

#pragma unroll 1
  for (int c = 0; c < NCH; ++c) {
    if (c + 1 < NCH) {
      asm volatile("s_waitcnt vmcnt(6)" ::: "memory");  // STAGE(c) landed
    } else {
      asm volatile("s_waitcnt vmcnt(0)" ::: "memory");
    }
    __builtin_amdgcn_s_barrier();
    __builtin_amdgcn_sched_barrier(0);
    if (c + 2 < NCH) STAGE(c + 2);    // overwrites buf (c-1)%3: sealed above

    const char* lq = lds + (c % 3) * 24576;
    const char* la = lq + arow * 256;
    // A fragments (swizzle-inverted units), kh = k-half of the 64k chunk
    f32x4 a00 = dsr_f4(la + ((kq * 2 + 0) ^ am) * 16);       // kh=0
    f32x4 a01 = dsr_f4(la + ((kq * 2 + 1) ^ am) * 16);
    f32x4 a10 = dsr_f4(la + ((8 + kq * 2 + 0) ^ am) * 16);   // kh=1
    f32x4 a11 = dsr_f4(la + ((8 + kq * 2 + 1) ^ am) * 16);
    // B fragments: lane-major, conflict-free
    const char* lb0 = lq + 8192 + lane * 16;
    const char* lb1 = lq + 16384 + lane * 16;
    bf16x8 b0h = dsr_b8(lb0 + (fb + 0) * 1024);
    bf16x8 b0l = dsr_b8(lb0 + (fb + 1) * 1024);
    bf16x8 b1h = dsr_b8(lb0 + (fb + 2) * 1024);
    bf16x8 b1l = dsr_b8(lb0 + (fb + 3) * 1024);
    bf16x8 c0h = dsr_b8(lb1 + (fb + 0) * 1024);
    bf16x8 c0l = dsr_b8(lb1 + (fb + 1) * 1024);
    bf16x8 c1h = dsr_b8(lb1 + (fb + 2) * 1024);
    bf16x8 c1l = dsr_b8(lb1 + (fb + 3) * 1024);
    asm volatile("s_waitcnt lgkmcnt(0)" ::: "memory");
    __builtin_amdgcn_sched_barrier(0);  // rule #18: pin MFMAs below the wait

    bf16x8 ahi, alo;
    split8v(a00, a01, ahi, alo);
    acc[0] = __builtin_amdgcn_mfma_f32_16x16x32_bf16(ahi, b0h, acc[0], 0, 0, 0);
    acc[0] = __builtin_amdgcn_mfma_f32_16x16x32_bf16(alo, b0h, acc[0], 0, 0, 0);
    acc[0] = __builtin_amdgcn_mfma_f32_16x16x32_bf16(ahi, b0l, acc[0], 0, 0, 0);
    acc[1] = __builtin_amdgcn_mfma_f32_16x16x32_bf16(ahi, b1h, acc[1], 0, 0, 0);
    acc[1] = __builtin_amdgcn_mfma_f32_16x16x32_bf16(alo, b1h, acc[1], 0, 0, 0);
    acc[1] = __builtin_amdgcn_mfma_f32_16x16x32_bf16(ahi, b1l, acc[1], 0, 0, 0);
    split8v(a10, a11, ahi, alo);
    acc[0] = __builtin_amdgcn_mfma_f32_16x16x32_bf16(ahi, c0h, acc[0], 0, 0, 0);
    acc[0] = __builtin_amdgcn_mfma_f32_16x16x32_bf16(alo, c0h, acc[0], 0, 0, 0);
    acc[0] = __builtin_amdgcn_mfma_f32_16x16x32_bf16(ahi, c0l, acc[0], 0, 0, 0);
    acc[1] = __builtin_amdgcn_mfma_f32_16x16x32_bf16(ahi, c1h, acc[1], 0, 0, 0);
    acc[1] = __builtin_amdgcn_mfma_f32_16x16x32_bf16(alo, c1h, acc[1], 0, 0, 0);
    acc[1] = __builtin_amdgcn_mfma_f32_16x16x32_bf16(ahi, c1l, acc[1], 0, 0, 0);
  }
#undef STAGE

  // ---- epilogue: full-K logits, 16 tok x 32 exp per wave ----
  __syncthreads();                         // full drain; LDS reusable
  float* logits = (float*)lds;             // 8 KB (32 x 64)
  float* hist   = (float*)(lds + 8192);    // 256 B
  if (tid < 64) hist[tid] = 0.f;
  // D layout (m89/R6-verified): e-col = et*16+col, token-row = 4*kq+r
#pragma unroll
  for (int et2 = 0; et2 < 2; ++et2)
#pragma unroll
    for (int rr = 0; rr < 4; ++rr) {
      int t = tt * 16 + 4 * kq + rr;
      int e = eh * 32 + et2 * 16 + col;
      logits[t * 64 + ((e + t) & 63)] = acc[et2][rr];
    }
  __syncthreads();

  // ---- sigmoid + biased top-8 + normalize + LDS hist (proven tail) ----
  if (tid < 32) {
    const int t = tid, gt = tok0 + t;
    float key[8], sv[8];
    int   idx[8];
#pragma unroll
    for (int j = 0; j < 8; ++j) { key[j] = -1e30f; sv[j] = 0.f; idx[j] = 0; }

    for (int e = 0; e < NE; ++e) {
      float l = logits[t * 64 + ((e + t) & 63)];
      float s = 1.0f / (1.0f + expf(-l));
      float k = s + bias[e];
      // bubble-insert; strict > keeps lower index on ties (lax.top_k order)
      float ck = k, cv = s; int ci = e;
#pragma unroll
      for (int j = 0; j < 8; ++j) {
        bool g = ck > key[j];
        float tk = key[j], tv = sv[j]; int ti = idx[j];
        key[j] = g ? ck : tk; sv[j] = g ? cv : tv; idx[j] = g ? ci : ti;
        ck = g ? tk : ck;     cv = g ? tv : cv;    ci = g ? ti : ci;
      }
    }

    float sum = 1e-20f;
#pragma unroll
    for (int j = 0; j < 8; ++j) sum += sv[j];
    float inv = 1.0f / sum;
#pragma unroll
    for (int j = 0; j < 8; ++j) {
      out_scores[gt * 8 + j] = sv[j] * inv;
      out_idx[gt * 8 + j]    = (float)idx[j];
      atomicAdd(&hist[idx[j]], 1.0f);      // LDS atomic
    }
  }
  __syncthreads();
  if (tid < 64) wsH[(size_t)blockIdx.x * NE + tid] = hist[tid];
}

// ---------- k5: reduce per-block histograms -> counts (no atomics) ----------
__global__ __launch_bounds__(256)
void router_k5(const float* __restrict__ wsH, float* __restrict__ counts,
               int nblk) {
  __shared__ float part[256];
  const int e = threadIdx.x & 63, p = threadIdx.x >> 6;
  float s = 0.f;
  for (int b = p; b < nblk; b += 4) s += wsH[(size_t)b * NE + e];
  part[p * 64 + e] = s;
  __syncthreads();
  if (threadIdx.x < 64)
    counts[e] = part[e] + part[64 + e] + part[128 + e] + part[192 + e];
}

// ---------- helper kept for fallbacks ----------
__device__ __forceinline__ void split8(const float4& a0, const float4& a1,
                                       bf16x8& ahi, bf16x8& alo) {
  float av[8] = {a0.x, a0.y, a0.z, a0.w, a1.x, a1.y, a1.z, a1.w};
#pragma unroll
  for (int j = 0; j < 8; ++j) {
    unsigned xb = __float_as_uint(av[j]);
    unsigned hb = xb & 0xffff0000u;
    float lf = av[j] - __uint_as_float(hb);
    unsigned lb = __float_as_uint(lf);
    lb = lb + 0x7fffu + ((lb >> 16) & 1u);
    ahi[j] = (short)(hb >> 16);
    alo[j] = (short)(lb >> 16);
  }
}

// ---------- R6 proven mid-fallback (ws >= 1 MB): direct B-stream MFMA ------
__global__ __launch_bounds__(512, 2)
void router_mfma(const float* __restrict__ x, const ushort* __restrict__ ws,
                 const float* __restrict__ bias,
                 float* __restrict__ out_scores, float* __restrict__ out_idx,
                 float* __restrict__ counts) {
  __shared__ float logits[64 * 64];
  const int tid  = threadIdx.x;
  const int lane = tid & 63;
  const int wv   = tid >> 6;
  const int wt   = wv & 3;
  const int wk   = wv >> 2;
  const int tok0 = blockIdx.x * 64;
  const int col  = lane & 15;
  const int kq   = lane >> 4;
  const float* xrow = x + (size_t)(tok0 + wt * 16 + col) * DIM + wk * 2048 + 8 * kq;
  const ushort* wsl = ws + (size_t)lane * 8;
  f32x4 acc[4];
#pragma unroll
  for (int et = 0; et < 4; ++et) acc[et] = (f32x4){0.f, 0.f, 0.f, 0.f};
  const int s0 = wk * 64;
  float4 a0c = *(const float4*)(xrow + 0);
  float4 a1c = *(const float4*)(xrow + 4);
  bf16x8 bc[8];
#pragma unroll
  for (int f = 0; f < 8; ++f)
    bc[f] = *(const bf16x8*)(wsl + (size_t)(s0 * 8 + f) * 64 * 8);
#pragma unroll 1
  for (int ls = 0; ls < 64; ls += 2) {
    const int so = s0 + ls + 1;
    float4 a0o = *(const float4*)(xrow + (ls + 1) * 32);
    float4 a1o = *(const float4*)(xrow + (ls + 1) * 32 + 4);
    bf16x8 bo[8];
#pragma unroll
    for (int f = 0; f < 8; ++f)
      bo[f] = *(const bf16x8*)(wsl + (size_t)(so * 8 + f) * 64 * 8);
    {
      bf16x8 ahi, alo;
      split8(a0c, a1c, ahi, alo);
#pragma unroll
      for (int et = 0; et < 4; ++et) {
        acc[et] = __builtin_amdgcn_mfma_f32_16x16x32_bf16(ahi, bc[et * 2 + 0], acc[et], 0, 0, 0);
        acc[et] = __builtin_amdgcn_mfma_f32_16x16x32_bf16(alo, bc[et * 2 + 0], acc[et], 0, 0, 0);
        acc[et] = __builtin_amdgcn_mfma_f32_16x16x32_bf16(ahi, bc[et * 2 + 1], acc[et], 0, 0, 0);
      }
    }
    if (ls + 2 < 64) {
      const int se = s0 + ls + 2;
      a0c = *(const float4*)(xrow + (ls + 2) * 32);
      a1c = *(const float4*)(xrow + (ls + 2) * 32 + 4);
#pragma unroll
      for (int f = 0; f < 8; ++f)
        bc[f] = *(const bf16x8*)(wsl + (size_t)(se * 8 + f) * 64 * 8);
    }
    {
      bf16x8 ahi, alo;
      split8(a0o, a1o, ahi, alo);
#pragma unroll
      for (int et = 0; et < 4; ++et) {
        acc[et] = __builtin_amdgcn_mfma_f32_16x16x32_bf16(ahi, bo[et * 2 + 0], acc[et], 0, 0, 0);
        acc[et] = __builtin_amdgcn_mfma_f32_16x16x32_bf16(alo, bo[et * 2 + 0], acc[et], 0, 0, 0);
        acc[et] = __builtin_amdgcn_mfma_f32_16x16x32_bf16(ahi, bo[et * 2 + 1], acc[et], 0, 0, 0);
      }
    }
  }
  if (wk == 0) {
#pragma unroll
    for (int et = 0; et < 4; ++et)
#pragma unroll
      for (int r = 0; r < 4; ++r) {
        int t = wt * 16 + 4 * kq + r;
        int e = et * 16 + col;
        logits[t * 64 + ((e + t) & 63)] = acc[et][r];
      }
  }
  __syncthreads();
  if (wk == 1) {
#pragma unroll
    for (int et = 0; et < 4; ++et)
#pragma unroll
      for (int r = 0; r < 4; ++r) {
        int t = wt * 16 + 4 * kq + r;
        int e = et * 16 + col;
        logits[t * 64 + ((e + t) & 63)] += acc[et][r];
      }
  }
  __syncthreads();
  if (tid < 64) {
    const int t = tid, gt = tok0 + t;
    float key[8], sv[8]; int idx[8];
#pragma unroll
    for (int j = 0; j < 8; ++j) { key[j] = -1e30f; sv[j] = 0.f; idx[j] = 0; }
    for (int e = 0; e < NE; ++e) {
      float l = logits[t * 64 + ((e + t) & 63)];
      float s = 1.0f / (1.0f + expf(-l));
      float k = s + bias[e];
      float ck = k, cv = s; int ci = e;
#pragma unroll
      for (int j = 0; j < 8; ++j) {
        bool g = ck > key[j];
        float tk = key[j], tv = sv[j]; int ti = idx[j];
        key[j] = g ? ck : tk; sv[j] = g ? cv : tv; idx[j] = g ? ci : ti;
        ck = g ? tk : ck;     cv = g ? tv : cv;    ci = g ? ti : ci;
      }
    }
    float sum = 1e-20f;
#pragma unroll
    for (int j = 0; j < 8; ++j) sum += sv[j];
    float inv = 1.0f / sum;
#pragma unroll
    for (int j = 0; j < 8; ++j) {
      out_scores[gt * 8 + j] = sv[j] * inv;
      out_idx[gt * 8 + j]    = (float)idx[j];
      atomicAdd(&counts[idx[j]], 1.0f);
    }
  }
}

// ---------- R5 proven last-resort fallback (fp32 scalar-w) ----------
constexpr int KSTEP = 32;
constexpr int FNSTEP = DIM / KSTEP;
constexpr int ROWF4 = 9;
constexpr int BUF4  = 64 * ROWF4;

__global__ __launch_bounds__(512, 2)
void router_fallback(const float* __restrict__ x, const float* __restrict__ w,
                     const float* __restrict__ bias,
                     float* __restrict__ out_scores, float* __restrict__ out_idx,
                     float* __restrict__ counts) {
  __shared__ float4 lds4[2 * BUF4];
  float* ldsf = (float*)lds4;
  const int tid  = threadIdx.x;
  const int lane = tid & 63;
  const int eg   = __builtin_amdgcn_readfirstlane(tid >> 6);
  const int tok0 = blockIdx.x * 64;
  const int r0 = tid >> 3, j0 = tid & 7;
  const float* gp = &x[(size_t)(tok0 + r0) * DIM + j0 * 4];
  const int l0 = r0 * ROWF4 + j0;
  float acc[8];
#pragma unroll
  for (int e = 0; e < 8; ++e) acc[e] = 0.f;
  lds4[l0] = *(const float4*)gp;
  __syncthreads();
  const float* wbase = w + (size_t)eg * 8 * DIM;
#pragma unroll 1
  for (int c = 0; c < FNSTEP; ++c) {
    float4 pf;
    if (c + 1 < FNSTEP) pf = *(const float4*)(gp + (c + 1) * KSTEP);
    float xr[KSTEP];
    {
      const float4* xrow = lds4 + (c & 1) * BUF4 + lane * ROWF4;
#pragma unroll
      for (int i = 0; i < 8; ++i) {
        float4 q = xrow[i];
        xr[4 * i + 0] = q.x; xr[4 * i + 1] = q.y;
        xr[4 * i + 2] = q.z; xr[4 * i + 3] = q.w;
      }
    }
#pragma unroll
    for (int e = 0; e < 8; ++e) {
      const float* wr = wbase + e * DIM + c * KSTEP;
#pragma unroll
      for (int k = 0; k < KSTEP; ++k) acc[e] = fmaf(xr[k], wr[k], acc[e]);
    }
    if (c + 1 < FNSTEP) lds4[((c + 1) & 1) * BUF4 + l0] = pf;
    __syncthreads();
  }
#pragma unroll
  for (int j = 0; j < 8; ++j) {
    int e = eg * 8 + j;
    ldsf[lane * 64 + ((e + lane) & 63)] = acc[j];
  }
  __syncthreads();
  if (tid < 64) {
    const int t = tid, gt = tok0 + t;
    float key[8], sv[8]; int idx[8];
#pragma unroll
    for (int j = 0; j < 8; ++j) { key[j] = -1e30f; sv[j] = 0.f; idx[j] = 0; }
    for (int e = 0; e < NE; ++e) {
      float l = ldsf[t * 64 + ((e + t) & 63)];
      float s = 1.0f / (1.0f + expf(-l));
      float k = s + bias[e];
      float ck = k, cv = s; int ci = e;
#pragma unroll
      for (int j = 0; j < 8; ++j) {
        bool g = ck > key[j];
        float tk = key[j], tv = sv[j]; int ti = idx[j];
        key[j] = g ? ck : tk; sv[j] = g ? cv : tv; idx[j] = g ? ci : ti;
        ck = g ? tk : ck;     cv = g ? tv : cv;    ci = g ? ti : ci;
      }
    }
    float sum = 1e-20f;
#pragma unroll
    for (int j = 0; j < 8; ++j) sum += sv[j];
    float inv = 1.0f / sum;
#pragma unroll
    for (int j = 0; j < 8; ++j) {
      out_scores[gt * 8 + j] = sv[j] * inv;
      out_idx[gt * 8 + j]    = (float)idx[j];
      atomicAdd(&counts[idx[j]], 1.0f);
    }
  }
}

extern "C" void kernel_launch(void* const* d_in, const int* in_sizes, int n_in,
                              void* d_out, int out_size, void* d_ws, size_t ws_size,
                              hipStream_t stream) {
  const float* x    = (const float*)d_in[0];
  const float* w    = (const float*)d_in[1];
  const float* bias = (const float*)d_in[2];

  const int ntok = in_sizes[0] / DIM;              // 16384
  float* out        = (float*)d_out;
  float* out_scores = out;
  float* out_idx    = out + ntok * 8;
  float* counts     = out + 2 * ntok * 8;

  hipMemsetAsync(counts, 0, NE * sizeof(float), stream);

  const int    nblk      = ntok / 32;              // 512
  const size_t wsh_bytes = (size_t)nblk * NE * sizeof(float);  // 128 KB
  const size_t need = WSB_BYTES + wsh_bytes;

  if (ws_size >= need && (ntok % 32) == 0) {
    ushort* wsB = (ushort*)d_ws;
    float*  wsH = (float*)((char*)d_ws + WSB_BYTES);
    hipLaunchKernelGGL(pack_w, dim3(256), dim3(256), 0, stream, w, wsB);
    hipLaunchKernelGGL(router_fused, dim3(nblk), dim3(256), 0, stream,
                       x, (const char*)wsB, bias, out_scores, out_idx, wsH);
    hipLaunchKernelGGL(router_k5, dim3(1), dim3(256), 0, stream,
                       wsH, counts, nblk);
  } else if (ws_size >= WSB_BYTES) {
    ushort* wsB = (ushort*)d_ws;
    hipLaunchKernelGGL(pack_w, dim3(256), dim3(256), 0, stream, w, wsB);
    hipLaunchKernelGGL(router_mfma, dim3(ntok / 64), dim3(512), 0, stream,
                       x, wsB, bias, out_scores, out_idx, counts);
  } else {
    hipLaunchKernelGGL(router_fallback, dim3(ntok / 64), dim3(512), 0, stream,
                       x, w, bias, out_scores, out_idx, counts);
  }
}